// Round 15
// baseline (122.458 us; speedup 1.0000x reference)
//
#include <hip/hip_runtime.h>
#include <math.h>

#define DIM 64
#define HEADS 4
#define BB 8
#define QQ 128
#define VV 128
#define NN (BB*QQ)   // 1024

typedef float f2 __attribute__((ext_vector_type(2)));
typedef float f4 __attribute__((ext_vector_type(4)));

// ---- DPP helpers (VALU, no DS); CTRL is a compile-time template constant ----
template <int CTRL>
__device__ __forceinline__ float dppf(float x) {
    return __int_as_float(__builtin_amdgcn_update_dpp(
        0, __float_as_int(x), CTRL, 0xF, 0xF, true));
}
#define SWAP1 0xB1   // quad_perm(1,0,3,2): xor-1 partner
#define WSHR1 0x138  // wave_shr:1 : lane j <- j-1
#define WSHL1 0x130  // wave_shl:1 : lane j <- j+1

// K1: Av_t[h][b][j][v] = f32 (re,im) of sum_i values[b*128+v,i] * U[h, 64+i, j]
// Math identical to before; store is lane-strided (transposed layout) so that
// k_rnn's per-lane step stream is CONTIGUOUS (L1-resident, dwordx4-loadable).
__global__ __launch_bounds__(256) void k_av(const float* __restrict__ values,
                                            const float* __restrict__ U_re,
                                            const float* __restrict__ U_im,
                                            f2* __restrict__ Av) {
    int tid = blockIdx.x * blockDim.x + threadIdx.x;
    int w = tid >> 6;            // 0..2047
    int j = tid & 63;
    int h = w >> 9;              // 0..3
    int r0 = (w & 511) << 1;     // first of 2 rows (global row = b*128+v)
    const float* vrow = values + r0 * DIM;                     // wave-uniform
    const float* ur = U_re + (h * 2 * DIM + DIM) * DIM + j;    // bottom half
    const float* ui = U_im + (h * 2 * DIM + DIM) * DIM + j;
    f2 a0 = 0.f, a1 = 0.f;
    #pragma unroll 8
    for (int i = 0; i < DIM; ++i) {
        f2 u; u.x = ur[i * DIM]; u.y = ui[i * DIM];
        a0 += vrow[i] * u;                 // s_load scalars broadcast
        a1 += vrow[DIM + i] * u;
    }
    // transposed store: [h][b][j][v], v = row & 127, b = row >> 7
    int b0 = r0 >> 7, v0 = r0 & 127;
    Av[(((h * BB + b0) * DIM) + j) * VV + v0] = a0;
    int r1 = r0 + 1;
    int b1 = r1 >> 7, v1 = r1 & 127;
    Av[(((h * BB + b1) * DIM) + j) * VV + v1] = a1;
}

// K2: 1024 blocks (block = row n) -> 4 waves/SIMD. 4 waves = 4 heads; each
// wave scans ONE row, lean step (~40 inst). Av stream per lane is contiguous:
// dwordx4 = 2 steps/load, 64-B line = 8 steps -> 7/8 loads L1-hit.
__global__ __launch_bounds__(256, 4) void k_rnn_dense(
        const float* __restrict__ queries,
        const float* __restrict__ U_re,
        const float* __restrict__ U_im,
        const float* __restrict__ bias,
        const float* __restrict__ theta1,
        const float* __restrict__ phi1,
        const float* __restrict__ theta2,
        const float* __restrict__ phi2,
        const float* __restrict__ omega,
        const f4* __restrict__ Av,        // [h][b][j][v/2] as f4 (2 steps)
        const float* __restrict__ W_dense,
        const float* __restrict__ b_dense,
        float* __restrict__ y) {
    int n = blockIdx.x;        // 0..1023 (row)
    int t = threadIdx.x;
    int h = t >> 6;            // head = wave
    int j = t & 63;            // state dim = lane
    int b = n >> 7;

    // ---- layer 1: t = E1 .* (C1*h + S1*swap1(h)) ----
    int k1 = j >> 1;
    float th1 = theta1[h * 32 + k1], ph1 = phi1[h * 32 + k1];
    float C1 = cosf(th1), s1v = sinf(th1);
    float S1, E1r, E1i;
    if ((j & 1) == 0) { S1 = -s1v; E1r = cosf(ph1); E1i = sinf(ph1); }
    else              { S1 =  s1v; E1r = 1.f;       E1i = 0.f;       }

    // ---- layer 2: s = PH .* (C2*t + SL*shl1(t) + SR*shr1(t)) ----
    float C2, SL, SR, p2r, p2i;
    if (j == 0 || j == 63) {
        C2 = 1.f; SL = 0.f; SR = 0.f; p2r = 1.f; p2i = 0.f;
    } else {
        int k2 = (j - 1) >> 1;
        float th2 = theta2[h * 31 + k2], ph2 = phi2[h * 31 + k2];
        float c2 = cosf(th2), s2 = sinf(th2);
        if (j & 1) { C2 = c2; SL = -s2; SR = 0.f; p2r = cosf(ph2); p2i = sinf(ph2); }
        else       { C2 = c2; SR =  s2; SL = 0.f; p2r = 1.f;       p2i = 0.f;       }
    }
    float om = omega[h * 64 + j];
    float eor = cosf(om), eoi = sinf(om);
    float PHr = p2r * eor - p2i * eoi;
    float PHi = p2r * eoi + p2i * eor;
    float bj = bias[h * 64 + j];

    // ---- Aq: uq = q_row . U_top[h]; query row block-uniform -> s_load ----
    const float* qrow = queries + n * DIM;
    const float* ur = U_re + (h * 2 * DIM) * DIM + j;
    const float* ui = U_im + (h * 2 * DIM) * DIM + j;
    float uqr = 0.f, uqi = 0.f;
    #pragma unroll 8
    for (int i = 0; i < DIM; ++i) {
        float a = qrow[i];
        uqr = fmaf(a, ur[i * DIM], uqr);
        uqi = fmaf(a, ui[i * DIM], uqi);
    }

    float hr = 0.f, hi = 0.f;
    auto step = [&](float avx, float avy) {
        float uvr = uqr + avx;             // off-chain input term
        float uvi = uqi + avy;
        // layer 1: real Givens + phase (even lanes)
        float pr = dppf<SWAP1>(hr), pi = dppf<SWAP1>(hi);
        float tpr = fmaf(C1, hr, S1 * pr);
        float tpi = fmaf(C1, hi, S1 * pi);
        float Tr = fmaf(E1r, tpr, -E1i * tpi);
        float Ti = fmaf(E1r, tpi,  E1i * tpr);
        // layer 2: real 3-tap + fused phase
        float Lr = dppf<WSHL1>(Tr), Li = dppf<WSHL1>(Ti);
        float Rr = dppf<WSHR1>(Tr), Ri = dppf<WSHR1>(Ti);
        float spr = fmaf(C2, Tr, fmaf(SL, Lr, SR * Rr));
        float spi = fmaf(C2, Ti, fmaf(SL, Li, SR * Ri));
        float zr = fmaf(PHr, spr, fmaf(-PHi, spi, uvr));
        float zi = fmaf(PHr, spi, fmaf( PHi, spr, uvi));
        // modrelu: sc = max(1 + b*rsq(|z|^2+eps), 0)  (1/m == rsq)
        float q2 = fmaf(zr, zr, fmaf(zi, zi, 1e-10f));
        float rs = __builtin_amdgcn_rsqf(q2);
        float sc = fmaxf(fmaf(bj, rs, 1.f), 0.f);
        hr = zr * sc; hi = zi * sc;
    };

    // lane-contiguous stream: Av[((h*8+b)*64+j)*64 + v/2] (f4 = 2 steps)
    const f4* p = Av + (((h * BB + b) * DIM) + j) * (VV / 2);

    // batch of 8 steps = 4 dwordx4 loads, double-buffered in registers
    f4 buf[4], nxt[4];
    #pragma unroll
    for (int k = 0; k < 4; ++k) buf[k] = p[k];

    for (int vb = 0; vb < VV; vb += 8) {
        const f4* pn = p + ((vb < VV - 8) ? 4 : 0);
        #pragma unroll
        for (int k = 0; k < 4; ++k) nxt[k] = pn[k];
        p = pn;
        #pragma unroll
        for (int k = 0; k < 4; ++k) {
            step(buf[k].x, buf[k].y);
            step(buf[k].z, buf[k].w);
        }
        #pragma unroll
        for (int k = 0; k < 4; ++k) buf[k] = nxt[k];
    }

    // ---- fused dense for row n ----
    __shared__ float s_acc[HEADS * DIM];   // 256
    __shared__ float s_part[256];
    s_acc[h * 64 + j] = hr;                // Re(hT)
    __syncthreads();

    {   // thread t: k-quarter qq = t>>6, col jj = t&63
        int qq = t >> 6, jj = t & 63;
        const float* Wp = W_dense + (qq * 64) * DIM + jj;
        const float* ap = &s_acc[qq * 64];
        float part = 0.f;
        #pragma unroll 8
        for (int k = 0; k < 64; ++k)
            part = fmaf(ap[k], Wp[k * DIM], part);   // ap broadcast, Wp coalesced
        s_part[t] = part;
    }
    __syncthreads();
    if (t < 64) {
        y[n * DIM + t] = b_dense[t] + s_part[t] + s_part[64 + t]
                       + s_part[128 + t] + s_part[192 + t];
    }
}

extern "C" void kernel_launch(void* const* d_in, const int* in_sizes, int n_in,
                              void* d_out, int out_size, void* d_ws, size_t ws_size,
                              hipStream_t stream) {
    const float* queries = (const float*)d_in[0];
    const float* values  = (const float*)d_in[1];
    const float* U_re    = (const float*)d_in[2];
    const float* U_im    = (const float*)d_in[3];
    const float* bias    = (const float*)d_in[4];
    const float* theta1  = (const float*)d_in[5];
    const float* phi1    = (const float*)d_in[6];
    const float* theta2  = (const float*)d_in[7];
    const float* phi2    = (const float*)d_in[8];
    const float* omega   = (const float*)d_in[9];
    const float* W_dense = (const float*)d_in[10];
    const float* b_dense = (const float*)d_in[11];
    float* y = (float*)d_out;

    f2* Av = (f2*)d_ws;   // transposed [h][b][j][v], 2 MB

    k_av<<<512, 256, 0, stream>>>(values, U_re, U_im, Av);
    k_rnn_dense<<<1024, 256, 0, stream>>>(queries, U_re, U_im, bias, theta1,
                                          phi1, theta2, phi2, omega, (const f4*)Av,
                                          W_dense, b_dense, y);
}

// Round 16
// 116.491 us; speedup vs baseline: 1.0512x; 1.0512x over previous
//
#include <hip/hip_runtime.h>
#include <math.h>

#define DIM 64
#define HEADS 4
#define BB 8
#define QQ 128
#define VV 128
#define NN (BB*QQ)   // 1024

typedef float f2 __attribute__((ext_vector_type(2)));

// ---- DPP helpers (VALU, no DS); CTRL is a compile-time template constant ----
template <int CTRL>
__device__ __forceinline__ float dppf(float x) {
    return __int_as_float(__builtin_amdgcn_update_dpp(
        0, __float_as_int(x), CTRL, 0xF, 0xF, true));
}
#define SWAP1 0xB1   // quad_perm(1,0,3,2): xor-1 partner
#define WSHR1 0x138  // wave_shr:1 : lane j <- j-1
#define WSHL1 0x130  // wave_shl:1 : lane j <- j+1

// K1: Av[h][row][j] = f32 (re,im) of sum_i values[row,i] * U[h, 64+i, j]
// (R14 layout: [h][row][j], coalesced stores; k_rnn loads 512B/wave/step)
__global__ __launch_bounds__(256) void k_av(const float* __restrict__ values,
                                            const float* __restrict__ U_re,
                                            const float* __restrict__ U_im,
                                            f2* __restrict__ Av) {
    int tid = blockIdx.x * blockDim.x + threadIdx.x;
    int w = tid >> 6;            // 0..2047
    int j = tid & 63;
    int h = w >> 9;              // 0..3
    int r0 = (w & 511) << 1;     // first of 2 rows within head h
    const float* vrow = values + r0 * DIM;                     // wave-uniform
    const float* ur = U_re + (h * 2 * DIM + DIM) * DIM + j;    // bottom half
    const float* ui = U_im + (h * 2 * DIM + DIM) * DIM + j;
    f2 a0 = 0.f, a1 = 0.f;
    #pragma unroll 8
    for (int i = 0; i < DIM; ++i) {
        f2 u; u.x = ur[i * DIM]; u.y = ui[i * DIM];
        a0 += vrow[i] * u;                 // s_load scalars broadcast
        a1 += vrow[DIM + i] * u;
    }
    f2* out = Av + (h * 1024 + r0) * DIM + j;
    out[0] = a0; out[DIM] = a1;
}

// K2: 1024 blocks (block = row n) -> 4 waves/SIMD (parallelism cap). 4 waves
// = 4 heads; each wave scans ONE row. Every cross-lane op is written in
// GCNDPPCombine's canonical form (single-use dpp in src0 of an accumulating
// fma) so the 6 dpp movs/step fuse into v_fmac_f32_dpp. Ping-pong Av buffers
// (no rotate copies).
__global__ __launch_bounds__(256, 4) void k_rnn_dense(
        const float* __restrict__ queries,
        const float* __restrict__ U_re,
        const float* __restrict__ U_im,
        const float* __restrict__ bias,
        const float* __restrict__ theta1,
        const float* __restrict__ phi1,
        const float* __restrict__ theta2,
        const float* __restrict__ phi2,
        const float* __restrict__ omega,
        const f2* __restrict__ Av,
        const float* __restrict__ W_dense,
        const float* __restrict__ b_dense,
        float* __restrict__ y) {
    int n = blockIdx.x;        // 0..1023 (row)
    int t = threadIdx.x;
    int h = t >> 6;            // head = wave
    int j = t & 63;            // state dim = lane
    int b = n >> 7;

    // ---- layer 1: t = E1 .* (C1*h + S1*swap1(h)) ----
    int k1 = j >> 1;
    float th1 = theta1[h * 32 + k1], ph1 = phi1[h * 32 + k1];
    float C1 = cosf(th1), s1v = sinf(th1);
    float S1, E1r, E1i;
    if ((j & 1) == 0) { S1 = -s1v; E1r = cosf(ph1); E1i = sinf(ph1); }
    else              { S1 =  s1v; E1r = 1.f;       E1i = 0.f;       }
    float nE1i = -E1i;

    // ---- layer 2: s = PH .* (C2*t + SL*shl1(t) + SR*shr1(t)) ----
    float C2, SL, SR, p2r, p2i;
    if (j == 0 || j == 63) {
        C2 = 1.f; SL = 0.f; SR = 0.f; p2r = 1.f; p2i = 0.f;
    } else {
        int k2 = (j - 1) >> 1;
        float th2 = theta2[h * 31 + k2], ph2 = phi2[h * 31 + k2];
        float c2 = cosf(th2), s2 = sinf(th2);
        if (j & 1) { C2 = c2; SL = -s2; SR = 0.f; p2r = cosf(ph2); p2i = sinf(ph2); }
        else       { C2 = c2; SR =  s2; SL = 0.f; p2r = 1.f;       p2i = 0.f;       }
    }
    float om = omega[h * 64 + j];
    float eor = cosf(om), eoi = sinf(om);
    float PHr = p2r * eor - p2i * eoi;
    float PHi = p2r * eoi + p2i * eor;
    float nPHi = -PHi;
    float bj = bias[h * 64 + j];

    // ---- Aq: uq = q_row . U_top[h]; query row block-uniform -> s_load ----
    const float* qrow = queries + n * DIM;
    const float* ur = U_re + (h * 2 * DIM) * DIM + j;
    const float* ui = U_im + (h * 2 * DIM) * DIM + j;
    float uqr = 0.f, uqi = 0.f;
    #pragma unroll 8
    for (int i = 0; i < DIM; ++i) {
        float a = qrow[i];
        uqr = fmaf(a, ur[i * DIM], uqr);
        uqi = fmaf(a, ui[i * DIM], uqi);
    }

    float hr = 0.f, hi = 0.f;
    auto step = [&](f2 av) {
        float uvr = uqr + av.x;            // off-chain input term
        float uvi = uqi + av.y;
        // layer 1 real mix — canonical fusion form: acc = C*x; acc += dpp(x)*S
        float tpr = C1 * hr;  tpr = fmaf(dppf<SWAP1>(hr), S1, tpr);
        float tpi = C1 * hi;  tpi = fmaf(dppf<SWAP1>(hi), S1, tpi);
        // phase E1 (free neg modifier via nE1i)
        float Tr = fmaf(E1r, tpr, nE1i * tpi);
        float Ti = fmaf(E1r, tpi, E1i * tpr);
        // layer 2 real 3-tap — canonical fusion form
        float spr = C2 * Tr;
        spr = fmaf(dppf<WSHL1>(Tr), SL, spr);
        spr = fmaf(dppf<WSHR1>(Tr), SR, spr);
        float spi = C2 * Ti;
        spi = fmaf(dppf<WSHL1>(Ti), SL, spi);
        spi = fmaf(dppf<WSHR1>(Ti), SR, spi);
        // phase PH + input
        float zr = fmaf(PHr, spr, fmaf(nPHi, spi, uvr));
        float zi = fmaf(PHr, spi, fmaf(PHi, spr, uvi));
        // modrelu: sc = max(1 + b*rsq(|z|^2+eps), 0)  (1/m == rsq)
        float q2 = fmaf(zr, zr, fmaf(zi, zi, 1e-10f));
        float rs = __builtin_amdgcn_rsqf(q2);
        float sc = fmaxf(fmaf(bj, rs, 1.f), 0.f);
        hr = zr * sc; hi = zi * sc;
    };

    const f2* p = Av + (h * 1024 + b * 128) * DIM + j;

    // ping-pong batches of 8 (no rotate copies)
    f2 bufA[8], bufB[8];
    #pragma unroll
    for (int k = 0; k < 8; ++k) bufA[k] = p[k * DIM];

    for (int vb = 0; vb < VV; vb += 16) {
        // load B (steps vb+8..15)
        const f2* pB = p + 8 * DIM;
        #pragma unroll
        for (int k = 0; k < 8; ++k) bufB[k] = pB[k * DIM];
        // compute A (steps vb..vb+7)
        #pragma unroll
        for (int k = 0; k < 8; ++k) step(bufA[k]);
        // load next A (steps vb+16..23; clamp on last iteration)
        const f2* pA = p + ((vb < VV - 16) ? 16 * DIM : 0);
        #pragma unroll
        for (int k = 0; k < 8; ++k) bufA[k] = pA[k * DIM];
        // compute B
        #pragma unroll
        for (int k = 0; k < 8; ++k) step(bufB[k]);
        p = pA;
    }

    // ---- fused dense for row n ----
    __shared__ float s_acc[HEADS * DIM];   // 256
    __shared__ float s_part[256];
    s_acc[h * 64 + j] = hr;                // Re(hT)
    __syncthreads();

    {   // thread t: k-quarter qq = t>>6, col jj = t&63
        int qq = t >> 6, jj = t & 63;
        const float* Wp = W_dense + (qq * 64) * DIM + jj;
        const float* ap = &s_acc[qq * 64];
        float part = 0.f;
        #pragma unroll 8
        for (int k = 0; k < 64; ++k)
            part = fmaf(ap[k], Wp[k * DIM], part);   // ap broadcast, Wp coalesced
        s_part[t] = part;
    }
    __syncthreads();
    if (t < 64) {
        y[n * DIM + t] = b_dense[t] + s_part[t] + s_part[64 + t]
                       + s_part[128 + t] + s_part[192 + t];
    }
}

extern "C" void kernel_launch(void* const* d_in, const int* in_sizes, int n_in,
                              void* d_out, int out_size, void* d_ws, size_t ws_size,
                              hipStream_t stream) {
    const float* queries = (const float*)d_in[0];
    const float* values  = (const float*)d_in[1];
    const float* U_re    = (const float*)d_in[2];
    const float* U_im    = (const float*)d_in[3];
    const float* bias    = (const float*)d_in[4];
    const float* theta1  = (const float*)d_in[5];
    const float* phi1    = (const float*)d_in[6];
    const float* theta2  = (const float*)d_in[7];
    const float* phi2    = (const float*)d_in[8];
    const float* omega   = (const float*)d_in[9];
    const float* W_dense = (const float*)d_in[10];
    const float* b_dense = (const float*)d_in[11];
    float* y = (float*)d_out;

    f2* Av = (f2*)d_ws;   // [h][row][j] f2 = 2 MB

    k_av<<<512, 256, 0, stream>>>(values, U_re, U_im, Av);
    k_rnn_dense<<<1024, 256, 0, stream>>>(queries, U_re, U_im, bias, theta1,
                                          phi1, theta2, phi2, omega, Av,
                                          W_dense, b_dense, y);
}